// Round 1
// baseline (1459.984 us; speedup 1.0000x reference)
//
#include <hip/hip_runtime.h>

// Problem constants
#define B_      4
#define N_      2048
#define KN      30      // neighbors
#define H_      8       // heads
#define D_      64      // head dim
#define CH      512     // NUM_HIDDEN
#define CI      640     // NUM_IN
#define CL      128     // NUM_LATENT
#define BN_TOT  8192    // B_*N_

typedef unsigned short u16;
typedef unsigned int   u32;

__device__ __forceinline__ float bf2f(u16 u) {
    return __uint_as_float(((u32)u) << 16);
}
__device__ __forceinline__ u16 f2bf(float f) {   // round-to-nearest-even
    u32 u = __float_as_uint(f);
    return (u16)((u + 0x7FFFu + ((u >> 16) & 1u)) >> 16);
}

#define NEG_INF (-3.4028234663852886e38f)

// ---------------------------------------------------------------------------
// Generic f32 tiled GEMM: C[MxN] = A[MxK] @ B[KxN], row-major, 64x64 tile,
// 256 threads, 4x4 micro-tile per thread.
// ---------------------------------------------------------------------------
__global__ __launch_bounds__(256) void gemm_f32_kernel(
    const float* __restrict__ A, const float* __restrict__ Bm,
    float* __restrict__ C, int M, int Nn, int Kk)
{
    __shared__ float As[16][68];   // [k][m], +4 pad
    __shared__ float Bs[16][68];   // [k][n]
    const int t  = threadIdx.x;
    const int m0 = blockIdx.y * 64;
    const int n0 = blockIdx.x * 64;
    const int ty = t >> 4, tx = t & 15;
    float acc[4][4] = {};
    for (int k0 = 0; k0 < Kk; k0 += 16) {
        {   // stage A 64x16 (transposed into As[k][m])
            int r = t >> 2, c4 = (t & 3) << 2;
            float4 av = *(const float4*)&A[(size_t)(m0 + r) * Kk + k0 + c4];
            As[c4 + 0][r] = av.x; As[c4 + 1][r] = av.y;
            As[c4 + 2][r] = av.z; As[c4 + 3][r] = av.w;
            // stage B 16x64
            int kk = t >> 4, n4 = (t & 15) << 2;
            *(float4*)&Bs[kk][n4] =
                *(const float4*)&Bm[(size_t)(k0 + kk) * Nn + n0 + n4];
        }
        __syncthreads();
#pragma unroll
        for (int kk = 0; kk < 16; kk++) {
            float4 a = *(const float4*)&As[kk][ty << 2];
            float4 b = *(const float4*)&Bs[kk][tx << 2];
            float ar[4] = {a.x, a.y, a.z, a.w};
            float br[4] = {b.x, b.y, b.z, b.w};
#pragma unroll
            for (int i = 0; i < 4; i++)
#pragma unroll
                for (int j = 0; j < 4; j++) acc[i][j] += ar[i] * br[j];
        }
        __syncthreads();
    }
#pragma unroll
    for (int i = 0; i < 4; i++) {
        float4 v = make_float4(acc[i][0], acc[i][1], acc[i][2], acc[i][3]);
        *(float4*)&C[(size_t)(m0 + (ty << 2) + i) * Nn + n0 + (tx << 2)] = v;
    }
}

// ---------------------------------------------------------------------------
// Qt[bn][h][c] = (1/8) * sum_d Q[bn][h*64+d] * W_K[c][h*64+d]   (bf16 out)
// Per-head GEMM: M=8192, K=64, N=640.  grid = (10, 128, 8)
// ---------------------------------------------------------------------------
__global__ __launch_bounds__(256) void qt_kernel(
    const float* __restrict__ Q, const float* __restrict__ WK,
    u16* __restrict__ Qt)
{
    __shared__ float As[16][68];   // [k][m]
    __shared__ float Bs[16][68];   // [k][c]
    const int t  = threadIdx.x;
    const int h  = blockIdx.z;
    const int m0 = blockIdx.y * 64;
    const int n0 = blockIdx.x * 64;   // over CI
    const int ty = t >> 4, tx = t & 15;
    float acc[4][4] = {};
    for (int k0 = 0; k0 < 64; k0 += 16) {
        {
            int r = t >> 2, c4 = (t & 3) << 2;
            float4 av = *(const float4*)&Q[(size_t)(m0 + r) * CH + h * 64 + k0 + c4];
            As[c4 + 0][r] = av.x; As[c4 + 1][r] = av.y;
            As[c4 + 2][r] = av.z; As[c4 + 3][r] = av.w;
            int kk = t & 15, cc0 = (t >> 4) << 2;
#pragma unroll
            for (int i = 0; i < 4; i++)
                Bs[kk][cc0 + i] = WK[(size_t)(n0 + cc0 + i) * CH + h * 64 + k0 + kk];
        }
        __syncthreads();
#pragma unroll
        for (int kk = 0; kk < 16; kk++) {
            float4 a = *(const float4*)&As[kk][ty << 2];
            float4 b = *(const float4*)&Bs[kk][tx << 2];
            float ar[4] = {a.x, a.y, a.z, a.w};
            float br[4] = {b.x, b.y, b.z, b.w};
#pragma unroll
            for (int i = 0; i < 4; i++)
#pragma unroll
                for (int j = 0; j < 4; j++) acc[i][j] += ar[i] * br[j];
        }
        __syncthreads();
    }
#pragma unroll
    for (int i = 0; i < 4; i++) {
        ushort4 sv;
        sv.x = f2bf(acc[i][0] * 0.125f);
        sv.y = f2bf(acc[i][1] * 0.125f);
        sv.z = f2bf(acc[i][2] * 0.125f);
        sv.w = f2bf(acc[i][3] * 0.125f);
        *(ushort4*)&Qt[((size_t)(m0 + (ty << 2) + i) * H_ + h) * CI + n0 + (tx << 2)] = sv;
    }
}

// ---------------------------------------------------------------------------
// biasL[b][k*8+h] = (z @ W_z)[b, k*8+h]
// ---------------------------------------------------------------------------
__global__ __launch_bounds__(256) void biasl_kernel(
    const float* __restrict__ z, const float* __restrict__ Wz,
    float* __restrict__ biasL)
{
    const int t = threadIdx.x;
    if (t < KN * H_) {
        for (int b = 0; b < B_; b++) {
            float s = 0.f;
            for (int l = 0; l < CL; l++) s += z[b * CL + l] * Wz[l * (KN * H_) + t];
            biasL[b * (KN * H_) + t] = s;
        }
    }
}

// ---------------------------------------------------------------------------
// Fused attention: one block per (b,n). h_E tile staged once in LDS (bf16).
// logits (Qt·hE, scale pre-folded) + bias_latent + bias_edges -> mask ->
// softmax -> attend*mask -> E_agg[h][c] = sum_k attend*hE  (bf16 out)
// ---------------------------------------------------------------------------
#define LDE 644   // LDS row stride in bf16: 322 dwords, %4==2 (8B-aligned), %32==2

__global__ __launch_bounds__(256) void attn_kernel(
    const float* __restrict__ hE, const float* __restrict__ mask,
    const u16* __restrict__ Qt, const float* __restrict__ Wb,
    const float* __restrict__ biasL, u16* __restrict__ Eagg)
{
    __shared__ u16   ehs[KN * LDE];       // 38640 B
    __shared__ float logit_s[H_ * KN];    // [h][k]
    __shared__ float att_s[KN * H_];      // [k][h] (transposed for vec reads)
    __shared__ float mask_s[KN];

    const int bn = blockIdx.x;
    const int b  = bn >> 11;              // N_=2048
    const int t  = threadIdx.x;

    // ---- stage h_E[b,n] -> LDS bf16 ----
    const float* he = hE + (size_t)bn * KN * CI;
    for (int idx = t; idx < KN * CI / 4; idx += 256) {   // 4800 float4 groups
        int k = idx / 160;                // 160 groups per row
        int c = (idx - k * 160) << 2;
        float4 v = *(const float4*)&he[k * CI + c];
        ushort4 sv;
        sv.x = f2bf(v.x); sv.y = f2bf(v.y); sv.z = f2bf(v.z); sv.w = f2bf(v.w);
        *(ushort4*)&ehs[k * LDE + c] = sv;
    }
    if (t < KN) mask_s[t] = mask[(size_t)bn * KN + t];
    __syncthreads();

    // ---- logits + biases + mask ----
    if (t < H_ * KN) {
        int h = t / KN, k = t - (t / KN) * KN;
        const u16* qrow = Qt + ((size_t)bn * H_ + h) * CI;
        const u16* erow = &ehs[k * LDE];
        float acc = 0.f;
        for (int c = 0; c < CI; c += 4) {
            ushort4 ev = *(const ushort4*)&erow[c];
            ushort4 qv = *(const ushort4*)&qrow[c];
            acc += bf2f(ev.x) * bf2f(qv.x) + bf2f(ev.y) * bf2f(qv.y)
                 + bf2f(ev.z) * bf2f(qv.z) + bf2f(ev.w) * bf2f(qv.w);
        }
        // bias_edges: h_E[...,33:] @ W_b  (column h)
        float acc2 = bf2f(erow[33]) * Wb[0 * H_ + h]
                   + bf2f(erow[34]) * Wb[1 * H_ + h]
                   + bf2f(erow[35]) * Wb[2 * H_ + h];
        for (int c = 36; c < CI; c += 4) {
            ushort4 ev = *(const ushort4*)&erow[c];
            const float* wb = &Wb[(c - 33) * H_ + h];
            acc2 += bf2f(ev.x) * wb[0] + bf2f(ev.y) * wb[8]
                  + bf2f(ev.z) * wb[16] + bf2f(ev.w) * wb[24];
        }
        float lg = acc + acc2 + biasL[b * (KN * H_) + k * H_ + h];
        lg = (mask_s[k] > 0.f) ? lg : NEG_INF;
        logit_s[h * KN + k] = lg;
    }
    __syncthreads();

    // ---- softmax over k, per head ----
    if (t < H_) {
        const int h = t;
        float m = NEG_INF;
#pragma unroll
        for (int k = 0; k < KN; k++) m = fmaxf(m, logit_s[h * KN + k]);
        float e[KN];
        float s = 0.f;
#pragma unroll
        for (int k = 0; k < KN; k++) { e[k] = __expf(logit_s[h * KN + k] - m); s += e[k]; }
        float inv = 1.f / s;
#pragma unroll
        for (int k = 0; k < KN; k++) att_s[k * H_ + h] = e[k] * inv * mask_s[k];
    }
    __syncthreads();

    // ---- E_agg[h][c] = sum_k attend[h][k] * hE[k][c] ----
    if (t < 160) {
        const int c0 = t << 2;
        float acc[8][4] = {};
        for (int k = 0; k < KN; k++) {
            ushort4 ev = *(const ushort4*)&ehs[k * LDE + c0];
            float f0 = bf2f(ev.x), f1 = bf2f(ev.y), f2 = bf2f(ev.z), f3 = bf2f(ev.w);
            float4 a0 = *(const float4*)&att_s[k * H_];
            float4 a1 = *(const float4*)&att_s[k * H_ + 4];
            float aw[8] = {a0.x, a0.y, a0.z, a0.w, a1.x, a1.y, a1.z, a1.w};
#pragma unroll
            for (int h = 0; h < 8; h++) {
                acc[h][0] += aw[h] * f0; acc[h][1] += aw[h] * f1;
                acc[h][2] += aw[h] * f2; acc[h][3] += aw[h] * f3;
            }
        }
#pragma unroll
        for (int h = 0; h < 8; h++) {
            ushort4 sv;
            sv.x = f2bf(acc[h][0]); sv.y = f2bf(acc[h][1]);
            sv.z = f2bf(acc[h][2]); sv.w = f2bf(acc[h][3]);
            *(ushort4*)&Eagg[((size_t)bn * H_ + h) * CI + c0] = sv;
        }
    }
}

// ---------------------------------------------------------------------------
// h_upd[m][h*64+d] = sum_c Eagg[m][h][c] * W_V[c][h*64+d]
// Per-head GEMM: M=8192, K=640, N=64.  grid = (1, 128, 8)
// ---------------------------------------------------------------------------
__global__ __launch_bounds__(256) void hupd_kernel(
    const u16* __restrict__ Eagg, const float* __restrict__ WV,
    float* __restrict__ Hupd)
{
    __shared__ float As[16][68];
    __shared__ float Bs[16][68];
    const int t  = threadIdx.x;
    const int h  = blockIdx.z;
    const int m0 = blockIdx.y * 64;
    const int ty = t >> 4, tx = t & 15;
    float acc[4][4] = {};
    for (int k0 = 0; k0 < CI; k0 += 16) {
        {
            int r = t >> 2, c4 = (t & 3) << 2;
            ushort4 ev = *(const ushort4*)&Eagg[((size_t)(m0 + r) * H_ + h) * CI + k0 + c4];
            As[c4 + 0][r] = bf2f(ev.x); As[c4 + 1][r] = bf2f(ev.y);
            As[c4 + 2][r] = bf2f(ev.z); As[c4 + 3][r] = bf2f(ev.w);
            int kk = t >> 4, d4 = (t & 15) << 2;
            *(float4*)&Bs[kk][d4] =
                *(const float4*)&WV[(size_t)(k0 + kk) * CH + h * 64 + d4];
        }
        __syncthreads();
#pragma unroll
        for (int kk = 0; kk < 16; kk++) {
            float4 a = *(const float4*)&As[kk][ty << 2];
            float4 b = *(const float4*)&Bs[kk][tx << 2];
            float ar[4] = {a.x, a.y, a.z, a.w};
            float br[4] = {b.x, b.y, b.z, b.w};
#pragma unroll
            for (int i = 0; i < 4; i++)
#pragma unroll
                for (int j = 0; j < 4; j++) acc[i][j] += ar[i] * br[j];
        }
        __syncthreads();
    }
#pragma unroll
    for (int i = 0; i < 4; i++) {
        float4 v = make_float4(acc[i][0], acc[i][1], acc[i][2], acc[i][3]);
        *(float4*)&Hupd[(size_t)(m0 + (ty << 2) + i) * CH + h * 64 + (tx << 2)] = v;
    }
}

// ---------------------------------------------------------------------------
extern "C" void kernel_launch(void* const* d_in, const int* in_sizes, int n_in,
                              void* d_out, int out_size, void* d_ws, size_t ws_size,
                              hipStream_t stream)
{
    const float* z    = (const float*)d_in[0];
    const float* hV   = (const float*)d_in[1];
    const float* hE   = (const float*)d_in[2];
    const float* mask = (const float*)d_in[3];
    const float* WQ   = (const float*)d_in[4];
    const float* WK   = (const float*)d_in[5];
    const float* WV   = (const float*)d_in[6];
    const float* WO   = (const float*)d_in[7];
    const float* Wz   = (const float*)d_in[8];
    const float* Wb   = (const float*)d_in[9];
    float* out = (float*)d_out;

    char* w = (char*)d_ws;
    // ws layout (184.6 MB total):
    //   [0, 16.78 MB)        Q (f32), later reused as Hupd (f32)
    //   [16.78, 100.66 MB)   Qt  (bf16)  8192*8*640
    //   [100.66, 184.55 MB)  Eagg(bf16)  8192*8*640
    //   [184.55 MB, +3840)   biasL (f32) 4*240
    float* Q     = (float*)w;
    u16*   Qt    = (u16*)(w + 16777216);
    u16*   Eagg  = (u16*)(w + 100663296);
    float* biasL = (float*)(w + 184549376);
    float* Hupd  = Q;   // Q is dead after qt_kernel

    // 1) Q = h_V @ W_Q
    gemm_f32_kernel<<<dim3(CH / 64, BN_TOT / 64), 256, 0, stream>>>(
        hV, WQ, Q, BN_TOT, CH, CH);
    // 2) bias_latent = z @ W_z
    biasl_kernel<<<1, 256, 0, stream>>>(z, Wz, biasL);
    // 3) Qt = per-head Q @ W_K^T, scaled by 1/8
    qt_kernel<<<dim3(CI / 64, BN_TOT / 64, H_), 256, 0, stream>>>(Q, WK, Qt);
    // 4) fused logits/softmax/aggregate over h_E (read once)
    attn_kernel<<<dim3(BN_TOT), 256, 0, stream>>>(hE, mask, Qt, Wb, biasL, Eagg);
    // 5) h_upd = per-head E_agg @ W_V
    hupd_kernel<<<dim3(1, BN_TOT / 64, H_), 256, 0, stream>>>(Eagg, WV, Hupd);
    // 6) out = h_upd @ W_O
    gemm_f32_kernel<<<dim3(CH / 64, BN_TOT / 64), 256, 0, stream>>>(
        Hupd, WO, out, BN_TOT, CH, CH);
}

// Round 2
// 1293.498 us; speedup vs baseline: 1.1287x; 1.1287x over previous
//
#include <hip/hip_runtime.h>

// Problem constants
#define B_      4
#define N_      2048
#define KN      30      // neighbors
#define H_      8       // heads
#define D_      64      // head dim
#define CH      512     // NUM_HIDDEN
#define CI      640     // NUM_IN
#define CL      128     // NUM_LATENT
#define BN_TOT  8192    // B_*N_

typedef unsigned short u16;
typedef unsigned int   u32;

typedef __attribute__((ext_vector_type(8))) short bf16x8;
typedef __attribute__((ext_vector_type(4))) float f32x4;

__device__ __forceinline__ float bf2f(u16 u) {
    return __uint_as_float(((u32)u) << 16);
}
__device__ __forceinline__ u16 f2bf(float f) {   // round-to-nearest-even
    u32 u = __float_as_uint(f);
    return (u16)((u + 0x7FFFu + ((u >> 16) & 1u)) >> 16);
}

#define NEG_INF (-3.4028234663852886e38f)

// async global->LDS, 16B per lane; LDS dest = wave-uniform base + lane*16
__device__ __forceinline__ void async16(const void* g, void* l) {
    __builtin_amdgcn_global_load_lds(
        (const __attribute__((address_space(1))) unsigned int*)g,
        (__attribute__((address_space(3))) unsigned int*)l, 16, 0, 0);
}

// ---------------------------------------------------------------------------
// f32 -> bf16 elementwise (n % 4 == 0)
// ---------------------------------------------------------------------------
__global__ __launch_bounds__(256) void cvt_kernel(
    const float* __restrict__ in, u16* __restrict__ out, int n)
{
    int i4 = (blockIdx.x * 256 + threadIdx.x) * 4;
    if (i4 < n) {
        float4 v = *(const float4*)&in[i4];
        ushort4 s;
        s.x = f2bf(v.x); s.y = f2bf(v.y); s.z = f2bf(v.z); s.w = f2bf(v.w);
        *(ushort4*)&out[i4] = s;
    }
}

// ---------------------------------------------------------------------------
// f32 (R x C) -> bf16 transposed (C x R): out[j*R + i] = in[i*C + j]
// ---------------------------------------------------------------------------
__global__ __launch_bounds__(256) void cvt_t_kernel(
    const float* __restrict__ in, u16* __restrict__ out, int R, int Cc)
{
    int o = blockIdx.x * 256 + threadIdx.x;
    if (o < R * Cc) {
        int j = o / R, i = o - j * R;
        out[o] = f2bf(in[(size_t)i * Cc + j]);
    }
}

// ---------------------------------------------------------------------------
// MFMA bf16 GEMM: C[128 x BN] += A[128 x K] * Bt[BN x K]^T  per z-slice.
// A row-major (lda), Bt row-major (ldb) = B^T, C row-major (ldc).
// 256 threads = 4 waves in 2x2 grid; wave tile 64 x (BN/2); 16x16x32 MFMA.
// Staging via global_load_lds width 16 (m97 structure).
// ---------------------------------------------------------------------------
template<int BN, bool BF16OUT>
__global__ __launch_bounds__(256) void mfma_gemm(
    const u16* __restrict__ A, const u16* __restrict__ Bt, void* __restrict__ Cp,
    int K, int lda, int ldb, int ldc,
    long aHead, long bHead, long cHead, float alpha)
{
    constexpr int WN = BN / 2;        // wave n-extent
    constexpr int NT = WN / 16;       // n-tiles per wave
    constexpr int BR = (BN * 4) / 256; // B staging rounds

    __shared__ u16 lA[128 * 32];
    __shared__ u16 lB[BN * 32];

    const int t    = threadIdx.x;
    const int w    = t >> 6;
    const int lane = t & 63;
    const int fr   = lane & 15;       // fragment row (m or n)
    const int fq   = lane >> 4;       // quad (k-chunk / acc row group)
    const int wm   = w >> 1, wn = w & 1;
    const int m0   = blockIdx.y * 128;
    const int n0   = blockIdx.x * BN;

    const u16* Ah = A  + (size_t)blockIdx.z * aHead;
    const u16* Bh = Bt + (size_t)blockIdx.z * bHead;

    f32x4 zero = {0.f, 0.f, 0.f, 0.f};
    f32x4 acc[4][NT];
#pragma unroll
    for (int i = 0; i < 4; i++)
#pragma unroll
        for (int j = 0; j < NT; j++) acc[i][j] = zero;

    for (int k0 = 0; k0 < K; k0 += 32) {
        // stage A tile 128x32 (2 rounds of 256 lanes x 16B)
#pragma unroll
        for (int r = 0; r < 2; r++) {
            int chunk = r * 256 + t;
            async16(Ah + (size_t)(m0 + (chunk >> 2)) * lda + k0 + ((chunk & 3) << 3),
                    &lA[(r * 256 + w * 64) * 8]);
        }
        // stage B tile BNx32
#pragma unroll
        for (int r = 0; r < BR; r++) {
            int chunk = r * 256 + t;
            async16(Bh + (size_t)(n0 + (chunk >> 2)) * ldb + k0 + ((chunk & 3) << 3),
                    &lB[(r * 256 + w * 64) * 8]);
        }
        __syncthreads();   // drains vmcnt before barrier

        bf16x8 af[4], bfr[NT];
#pragma unroll
        for (int i = 0; i < 4; i++)
            af[i] = *(const bf16x8*)&lA[(wm * 64 + i * 16 + fr) * 32 + fq * 8];
#pragma unroll
        for (int j = 0; j < NT; j++)
            bfr[j] = *(const bf16x8*)&lB[(wn * WN + j * 16 + fr) * 32 + fq * 8];
#pragma unroll
        for (int i = 0; i < 4; i++)
#pragma unroll
            for (int j = 0; j < NT; j++)
                acc[i][j] = __builtin_amdgcn_mfma_f32_16x16x32_bf16(
                    af[i], bfr[j], acc[i][j], 0, 0, 0);
        __syncthreads();
    }

    // epilogue: C/D layout col=lane&15, row=(lane>>4)*4+reg
    const size_t cbase = (size_t)blockIdx.z * cHead;
#pragma unroll
    for (int i = 0; i < 4; i++) {
        int row = m0 + wm * 64 + i * 16 + fq * 4;
#pragma unroll
        for (int j = 0; j < NT; j++) {
            int col = n0 + wn * WN + j * 16 + fr;
#pragma unroll
            for (int r = 0; r < 4; r++) {
                float v = acc[i][j][r] * alpha;
                if (BF16OUT)
                    ((u16*)Cp)[cbase + (size_t)(row + r) * ldc + col] = f2bf(v);
                else
                    ((float*)Cp)[cbase + (size_t)(row + r) * ldc + col] = v;
            }
        }
    }
}

// ---------------------------------------------------------------------------
// biasL[b][k*8+h] = (z @ W_z)[b, k*8+h]
// ---------------------------------------------------------------------------
__global__ __launch_bounds__(256) void biasl_kernel(
    const float* __restrict__ z, const float* __restrict__ Wz,
    float* __restrict__ biasL)
{
    const int t = threadIdx.x;
    if (t < KN * H_) {
        for (int b = 0; b < B_; b++) {
            float s = 0.f;
            for (int l = 0; l < CL; l++) s += z[b * CL + l] * Wz[l * (KN * H_) + t];
            biasL[b * (KN * H_) + t] = s;
        }
    }
}

// ---------------------------------------------------------------------------
// Fused attention: one block per (b,n). h_E tile staged once in LDS (bf16).
// logits (Qt·hE, scale pre-folded) + bias_latent + bias_edges -> mask ->
// softmax -> attend*mask -> E_agg[h][c] = sum_k attend*hE  (bf16 out)
// NOTE: Qt and Eagg may alias (in-place); reads and writes are to the same
// bn-slice, separated by __syncthreads. No __restrict__ on those params.
// ---------------------------------------------------------------------------
#define LDE 644   // LDS row stride in bf16

__global__ __launch_bounds__(256) void attn_kernel(
    const float* __restrict__ hE, const float* __restrict__ mask,
    const u16* Qt, const float* __restrict__ Wb,
    const float* __restrict__ biasL, u16* Eagg)
{
    __shared__ u16   ehs[KN * LDE];       // 38640 B
    __shared__ float logit_s[H_ * KN];    // [h][k]
    __shared__ float att_s[KN * H_];      // [k][h]
    __shared__ float mask_s[KN];

    const int bn = blockIdx.x;
    const int b  = bn >> 11;              // N_=2048
    const int t  = threadIdx.x;

    // ---- stage h_E[b,n] -> LDS bf16 ----
    const float* he = hE + (size_t)bn * KN * CI;
    for (int idx = t; idx < KN * CI / 4; idx += 256) {   // 4800 float4 groups
        int k = idx / 160;
        int c = (idx - k * 160) << 2;
        float4 v = *(const float4*)&he[k * CI + c];
        ushort4 sv;
        sv.x = f2bf(v.x); sv.y = f2bf(v.y); sv.z = f2bf(v.z); sv.w = f2bf(v.w);
        *(ushort4*)&ehs[k * LDE + c] = sv;
    }
    if (t < KN) mask_s[t] = mask[(size_t)bn * KN + t];
    __syncthreads();

    // ---- logits + biases + mask ----
    if (t < H_ * KN) {
        int h = t / KN, k = t - (t / KN) * KN;
        const u16* qrow = Qt + ((size_t)bn * H_ + h) * CI;
        const u16* erow = &ehs[k * LDE];
        float acc = 0.f;
        for (int c = 0; c < CI; c += 4) {
            ushort4 ev = *(const ushort4*)&erow[c];
            ushort4 qv = *(const ushort4*)&qrow[c];
            acc += bf2f(ev.x) * bf2f(qv.x) + bf2f(ev.y) * bf2f(qv.y)
                 + bf2f(ev.z) * bf2f(qv.z) + bf2f(ev.w) * bf2f(qv.w);
        }
        float acc2 = bf2f(erow[33]) * Wb[0 * H_ + h]
                   + bf2f(erow[34]) * Wb[1 * H_ + h]
                   + bf2f(erow[35]) * Wb[2 * H_ + h];
        for (int c = 36; c < CI; c += 4) {
            ushort4 ev = *(const ushort4*)&erow[c];
            const float* wb = &Wb[(c - 33) * H_ + h];
            acc2 += bf2f(ev.x) * wb[0] + bf2f(ev.y) * wb[8]
                  + bf2f(ev.z) * wb[16] + bf2f(ev.w) * wb[24];
        }
        float lg = acc + acc2 + biasL[b * (KN * H_) + k * H_ + h];
        lg = (mask_s[k] > 0.f) ? lg : NEG_INF;
        logit_s[h * KN + k] = lg;
    }
    __syncthreads();

    // ---- softmax over k, per head ----
    if (t < H_) {
        const int h = t;
        float m = NEG_INF;
#pragma unroll
        for (int k = 0; k < KN; k++) m = fmaxf(m, logit_s[h * KN + k]);
        float e[KN];
        float s = 0.f;
#pragma unroll
        for (int k = 0; k < KN; k++) { e[k] = __expf(logit_s[h * KN + k] - m); s += e[k]; }
        float inv = 1.f / s;
#pragma unroll
        for (int k = 0; k < KN; k++) att_s[k * H_ + h] = e[k] * inv * mask_s[k];
    }
    __syncthreads();

    // ---- E_agg[h][c] = sum_k attend[h][k] * hE[k][c] ----
    if (t < 160) {
        const int c0 = t << 2;
        float acc[8][4] = {};
        for (int k = 0; k < KN; k++) {
            ushort4 ev = *(const ushort4*)&ehs[k * LDE + c0];
            float f0 = bf2f(ev.x), f1 = bf2f(ev.y), f2 = bf2f(ev.z), f3 = bf2f(ev.w);
            float4 a0 = *(const float4*)&att_s[k * H_];
            float4 a1 = *(const float4*)&att_s[k * H_ + 4];
            float aw[8] = {a0.x, a0.y, a0.z, a0.w, a1.x, a1.y, a1.z, a1.w};
#pragma unroll
            for (int h = 0; h < 8; h++) {
                acc[h][0] += aw[h] * f0; acc[h][1] += aw[h] * f1;
                acc[h][2] += aw[h] * f2; acc[h][3] += aw[h] * f3;
            }
        }
#pragma unroll
        for (int h = 0; h < 8; h++) {
            ushort4 sv;
            sv.x = f2bf(acc[h][0]); sv.y = f2bf(acc[h][1]);
            sv.z = f2bf(acc[h][2]); sv.w = f2bf(acc[h][3]);
            *(ushort4*)&Eagg[((size_t)bn * H_ + h) * CI + c0] = sv;
        }
    }
}

// ---------------------------------------------------------------------------
extern "C" void kernel_launch(void* const* d_in, const int* in_sizes, int n_in,
                              void* d_out, int out_size, void* d_ws, size_t ws_size,
                              hipStream_t stream)
{
    const float* z    = (const float*)d_in[0];
    const float* hV   = (const float*)d_in[1];
    const float* hE   = (const float*)d_in[2];
    const float* mask = (const float*)d_in[3];
    const float* WQ   = (const float*)d_in[4];
    const float* WK   = (const float*)d_in[5];
    const float* WV   = (const float*)d_in[6];
    const float* WO   = (const float*)d_in[7];
    const float* Wz   = (const float*)d_in[8];
    const float* Wb   = (const float*)d_in[9];
    float* out = (float*)d_out;

    char* w = (char*)d_ws;
    // ws layout (~103 MB):
    //  [0,        8.39 MB)  hV_bf (bf16), reused as Hupd_bf after gemm1
    //  [8.39,    16.78 MB)  Q_bf  (bf16)
    //  [16.78,  100.66 MB)  Qt (bf16) 8192x8x640 — Eagg written IN-PLACE here
    //  [100.66 MB, +2.4 MB) WQt, WK_bf, WVt, WOt (bf16), biasL (f32)
    u16*   hV_bf = (u16*)w;
    u16*   Q_bf  = (u16*)(w + 8388608);
    u16*   Qt    = (u16*)(w + 16777216);
    u16*   WQt   = (u16*)(w + 100663296);
    u16*   WK_bf = (u16*)(w + 101187584);
    u16*   WVt   = (u16*)(w + 101842944);
    u16*   WOt   = (u16*)(w + 102498304);
    float* biasL = (float*)(w + 103022592);
    u16*   Eagg  = Qt;       // in-place
    u16*   Hupd  = hV_bf;    // hV_bf dead after gemm1

    // 0) conversions
    cvt_kernel<<<4096, 256, 0, stream>>>(hV, hV_bf, BN_TOT * CH);
    cvt_kernel<<<320, 256, 0, stream>>>(WK, WK_bf, CI * CH);
    cvt_t_kernel<<<1024, 256, 0, stream>>>(WQ, WQt, CH, CH);      // WQt[n][k]
    cvt_t_kernel<<<1280, 256, 0, stream>>>(WV, WVt, CI, CH);      // WVt[d][c]
    cvt_t_kernel<<<1024, 256, 0, stream>>>(WO, WOt, CH, CH);      // WOt[n][k]
    biasl_kernel<<<1, 256, 0, stream>>>(z, Wz, biasL);

    // 1) Q_bf = hV @ W_Q          (M=8192, N=512, K=512)
    mfma_gemm<128, true><<<dim3(4, 64, 1), 256, 0, stream>>>(
        hV_bf, WQt, Q_bf, CH, CH, CH, CH, 0, 0, 0, 1.0f);
    // 2) Qt = per-head (Q_h @ W_K_h^T) / 8   (M=8192, N=640, K=64, z=head)
    mfma_gemm<128, true><<<dim3(5, 64, H_), 256, 0, stream>>>(
        Q_bf, WK_bf, Qt, 64, CH, CH, H_ * CI, 64, 64, CI, 0.125f);
    // 3) fused logits/softmax/aggregate (Eagg in-place over Qt)
    attn_kernel<<<dim3(BN_TOT), 256, 0, stream>>>(hE, mask, Qt, Wb, biasL, Eagg);
    // 4) Hupd = per-head Eagg_h @ W_V_h      (M=8192, N=64, K=640, z=head)
    mfma_gemm<64, true><<<dim3(1, 64, H_), 256, 0, stream>>>(
        Eagg, WVt, Hupd, CI, H_ * CI, CI, CH, CI, 64L * CI, 64, 1.0f);
    // 5) out = Hupd @ W_O          (M=8192, N=512, K=512)
    mfma_gemm<128, false><<<dim3(4, 64, 1), 256, 0, stream>>>(
        Hupd, WOt, out, CH, CH, CH, CH, 0, 0, 0, 1.0f);
}